// Round 2
// baseline (1222.115 us; speedup 1.0000x reference)
//
#include <hip/hip_runtime.h>
#include <hip/hip_bf16.h>

// Problem sizes (fixed by the reference)
#define B_DIM 8192
#define IN_DIM 2048
#define H_DIM 2048

// GEMM tile config (m97 structure: 128x128 tile, 4 waves, BK=64)
#define BM 128
#define BN 128
#define BK 64

typedef __attribute__((ext_vector_type(8))) short short8;   // 8 bf16 = 4 VGPRs
typedef __attribute__((ext_vector_type(4))) float f32x4;    // MFMA accum

__device__ __forceinline__ unsigned short f2bf(float f) {
    // round-to-nearest-even fp32 -> bf16 (inputs are normal-range)
    unsigned u = __builtin_bit_cast(unsigned, f);
    u += 0x7fffu + ((u >> 16) & 1u);
    return (unsigned short)(u >> 16);
}

// ---------------------------------------------------------------------------
// fp32 -> bf16 conversion, vectorized: 8 floats in (2x float4), 8 bf16 out (uint4)
// ---------------------------------------------------------------------------
__global__ void __launch_bounds__(256) cvt_f32_bf16(const float* __restrict__ in,
                                                    unsigned short* __restrict__ out,
                                                    int n8) {
    int i = blockIdx.x * blockDim.x + threadIdx.x;
    const int stride = gridDim.x * blockDim.x;
    for (; i < n8; i += stride) {
        const float4* p = (const float4*)in + (size_t)i * 2;
        float4 f0 = p[0], f1 = p[1];
        uint4 o;
        o.x = (unsigned)f2bf(f0.x) | ((unsigned)f2bf(f0.y) << 16);
        o.y = (unsigned)f2bf(f0.z) | ((unsigned)f2bf(f0.w) << 16);
        o.z = (unsigned)f2bf(f1.x) | ((unsigned)f2bf(f1.y) << 16);
        o.w = (unsigned)f2bf(f1.z) | ((unsigned)f2bf(f1.w) << 16);
        ((uint4*)out)[i] = o;
    }
}

// ---------------------------------------------------------------------------
// GEMM main loop (shared by both kernels), m97 structure:
//   C[M,N] = A[M,K=4096] * B[N,K=4096]^T with the K-loop switching sources
//   at k=2048.  A/B staged to LDS via global_load_lds width=16, 2 barriers
//   per K-step, 16x16x32 bf16 MFMA, each of 4 waves owns a 64x64 subtile.
// ---------------------------------------------------------------------------
#define GEMM_MAIN_LOOP(A0, B0, A1, B1)                                         \
    f32x4 acc[4][4] = {};                                                      \
    const int tid = threadIdx.x;                                               \
    const int lane = tid & 63;                                                 \
    const int wave = tid >> 6;                                                 \
    const int wr = wave >> 1, wc = wave & 1;                                   \
    const int fm = lane & 15;                                                  \
    const int fk = (lane >> 4) << 3;                                           \
    const int s_r0 = tid >> 3;       /* staging row base 0..31 */              \
    const int s_c = (tid & 7) << 3;  /* staging col (elements) */              \
    for (int kt = 0; kt < 4096; kt += BK) {                                    \
        const unsigned short* Asrc;                                            \
        const unsigned short* Bsrc;                                            \
        int kk;                                                                \
        if (kt < 2048) { Asrc = (A0); Bsrc = (B0); kk = kt; }                  \
        else           { Asrc = (A1); Bsrc = (B1); kk = kt - 2048; }           \
        _Pragma("unroll")                                                      \
        for (int i = 0; i < 4; ++i) {                                          \
            const int r = i * 32 + s_r0;                                       \
            __builtin_amdgcn_global_load_lds(                                  \
                (const __attribute__((address_space(1))) void*)                \
                    (Asrc + (size_t)(brow + r) * 2048 + kk + s_c),             \
                (__attribute__((address_space(3))) void*)                      \
                    (&As[(i * 256 + tid) * 8]),                                \
                16, 0, 0);                                                     \
            __builtin_amdgcn_global_load_lds(                                  \
                (const __attribute__((address_space(1))) void*)                \
                    (Bsrc + (size_t)(bcol + r) * 2048 + kk + s_c),             \
                (__attribute__((address_space(3))) void*)                      \
                    (&Bs[(i * 256 + tid) * 8]),                                \
                16, 0, 0);                                                     \
        }                                                                      \
        __syncthreads();                                                       \
        _Pragma("unroll")                                                      \
        for (int ks = 0; ks < BK; ks += 32) {                                  \
            short8 a[4], b[4];                                                 \
            _Pragma("unroll")                                                  \
            for (int mi = 0; mi < 4; ++mi)                                     \
                a[mi] = *(const short8*)&As[(wr * 64 + mi * 16 + fm) * BK + ks + fk]; \
            _Pragma("unroll")                                                  \
            for (int ni = 0; ni < 4; ++ni)                                     \
                b[ni] = *(const short8*)&Bs[(wc * 64 + ni * 16 + fm) * BK + ks + fk]; \
            _Pragma("unroll")                                                  \
            for (int mi = 0; mi < 4; ++mi)                                     \
                _Pragma("unroll")                                              \
                for (int ni = 0; ni < 4; ++ni)                                 \
                    acc[mi][ni] = __builtin_amdgcn_mfma_f32_16x16x32_bf16(     \
                        a[mi], b[ni], acc[mi][ni], 0, 0, 0);                   \
        }                                                                      \
        __syncthreads();                                                       \
    }

// ---------------------------------------------------------------------------
// Kernel 1: r and z gates.  grid = 2048 blocks: [0,1024) -> r, [1024,2048) -> z
//   r = sigmoid(x@W_ir.T + b_ir + h@W_hr.T)   (+ stores rh = bf16(r*h))
//   z = sigmoid(x@W_iz.T + b_iz + h@W_hz.T)
// ---------------------------------------------------------------------------
__global__ void __launch_bounds__(256) gemm_rz(
    const unsigned short* __restrict__ xb, const unsigned short* __restrict__ hb,
    const unsigned short* __restrict__ Wir, const unsigned short* __restrict__ Whr,
    const unsigned short* __restrict__ Wiz, const unsigned short* __restrict__ Whz,
    const float* __restrict__ b_ir, const float* __restrict__ b_iz,
    const float* __restrict__ h_f32,
    float* __restrict__ out_r, float* __restrict__ out_z,
    unsigned short* __restrict__ rh)
{
    __shared__ __align__(16) unsigned short As[BM * BK];
    __shared__ __align__(16) unsigned short Bs[BN * BK];

    int bid = blockIdx.x;
    const int is_z = bid >= 1024;
    if (is_z) bid -= 1024;
    const int mt = bid & 63;
    const int nt = bid >> 6;
    const int brow = mt * BM;
    const int bcol = nt * BN;

    const unsigned short* Wi = is_z ? Wiz : Wir;
    const unsigned short* Wh = is_z ? Whz : Whr;

    GEMM_MAIN_LOOP(xb, Wi, hb, Wh)

    const float* bias = is_z ? b_iz : b_ir;
    float* outp = is_z ? out_z : out_r;

#pragma unroll
    for (int ni = 0; ni < 4; ++ni) {
        const int col = bcol + wc * 64 + ni * 16 + fm;
        const float bv = bias[col];
#pragma unroll
        for (int mi = 0; mi < 4; ++mi) {
            const int row0 = brow + wr * 64 + mi * 16 + (lane >> 4) * 4;
#pragma unroll
            for (int v = 0; v < 4; ++v) {
                const int idx = (row0 + v) * 2048 + col;
                float s = acc[mi][ni][v] + bv;
                s = 1.0f / (1.0f + __expf(-s));
                outp[idx] = s;
                if (!is_z) {
                    rh[idx] = f2bf(s * h_f32[idx]);
                }
            }
        }
    }
}

// ---------------------------------------------------------------------------
// Kernel 2: n gate + h_t.  grid = 1024 blocks.
//   n   = tanh(x@W_in.T + b_in + (r*h)@W_hn.T)
//   h_t = (1-z)*n + z*h
// ---------------------------------------------------------------------------
__global__ void __launch_bounds__(256) gemm_n(
    const unsigned short* __restrict__ xb, const unsigned short* __restrict__ rh,
    const unsigned short* __restrict__ Win, const unsigned short* __restrict__ Whn,
    const float* __restrict__ b_in,
    const float* __restrict__ h_f32, const float* __restrict__ out_z,
    float* __restrict__ out_n, float* __restrict__ out_ht)
{
    __shared__ __align__(16) unsigned short As[BM * BK];
    __shared__ __align__(16) unsigned short Bs[BN * BK];

    const int bid = blockIdx.x;
    const int mt = bid & 63;
    const int nt = bid >> 6;
    const int brow = mt * BM;
    const int bcol = nt * BN;

    GEMM_MAIN_LOOP(xb, Win, rh, Whn)

#pragma unroll
    for (int ni = 0; ni < 4; ++ni) {
        const int col = bcol + wc * 64 + ni * 16 + fm;
        const float bv = b_in[col];
#pragma unroll
        for (int mi = 0; mi < 4; ++mi) {
            const int row0 = brow + wr * 64 + mi * 16 + (lane >> 4) * 4;
#pragma unroll
            for (int v = 0; v < 4; ++v) {
                const int idx = (row0 + v) * 2048 + col;
                const float t = tanhf(acc[mi][ni][v] + bv);
                out_n[idx] = t;
                const float zv = out_z[idx];
                const float hv = h_f32[idx];
                out_ht[idx] = (1.0f - zv) * t + zv * hv;
            }
        }
    }
}

// ---------------------------------------------------------------------------
// Launch
// ---------------------------------------------------------------------------
extern "C" void kernel_launch(void* const* d_in, const int* in_sizes, int n_in,
                              void* d_out, int out_size, void* d_ws, size_t ws_size,
                              hipStream_t stream) {
    const float* x    = (const float*)d_in[0];
    const float* h    = (const float*)d_in[1];
    const float* W_ir = (const float*)d_in[2];
    const float* b_ir = (const float*)d_in[3];
    const float* W_hr = (const float*)d_in[4];
    const float* W_iz = (const float*)d_in[5];
    const float* b_iz = (const float*)d_in[6];
    const float* W_hz = (const float*)d_in[7];
    const float* W_in = (const float*)d_in[8];
    const float* b_in = (const float*)d_in[9];
    const float* W_hn = (const float*)d_in[10];

    const size_t NBH = (size_t)B_DIM * H_DIM;   // 16,777,216
    const size_t NW  = (size_t)H_DIM * IN_DIM;  // 4,194,304

    float* out_ht = (float*)d_out;
    float* out_r  = out_ht + NBH;
    float* out_z  = out_r + NBH;
    float* out_n  = out_z + NBH;

    unsigned short* ws   = (unsigned short*)d_ws;
    unsigned short* xb   = ws;
    unsigned short* hb   = xb + NBH;
    unsigned short* wirb = hb + NBH;
    unsigned short* whrb = wirb + NW;
    unsigned short* wizb = whrb + NW;
    unsigned short* whzb = wizb + NW;
    unsigned short* winb = whzb + NW;
    unsigned short* whnb = winb + NW;
    unsigned short* rh   = whnb + NW;
    // total ws use: (3*16.7M + 6*4.2M) * 2B  ~= 151 MB

    // fp32 -> bf16 conversions
    const int CVT_BLOCKS = 2048;
    cvt_f32_bf16<<<CVT_BLOCKS, 256, 0, stream>>>(x, xb, (int)(NBH / 8));
    cvt_f32_bf16<<<CVT_BLOCKS, 256, 0, stream>>>(h, hb, (int)(NBH / 8));
    cvt_f32_bf16<<<CVT_BLOCKS, 256, 0, stream>>>(W_ir, wirb, (int)(NW / 8));
    cvt_f32_bf16<<<CVT_BLOCKS, 256, 0, stream>>>(W_hr, whrb, (int)(NW / 8));
    cvt_f32_bf16<<<CVT_BLOCKS, 256, 0, stream>>>(W_iz, wizb, (int)(NW / 8));
    cvt_f32_bf16<<<CVT_BLOCKS, 256, 0, stream>>>(W_hz, whzb, (int)(NW / 8));
    cvt_f32_bf16<<<CVT_BLOCKS, 256, 0, stream>>>(W_in, winb, (int)(NW / 8));
    cvt_f32_bf16<<<CVT_BLOCKS, 256, 0, stream>>>(W_hn, whnb, (int)(NW / 8));

    // r and z gates (also produces rh = bf16(r*h))
    gemm_rz<<<2048, 256, 0, stream>>>(xb, hb, wirb, whrb, wizb, whzb,
                                      b_ir, b_iz, h, out_r, out_z, rh);

    // n gate + h_t
    gemm_n<<<1024, 256, 0, stream>>>(xb, rh, winb, whnb, b_in, h, out_z,
                                     out_n, out_ht);
}

// Round 5
// 1024.060 us; speedup vs baseline: 1.1934x; 1.1934x over previous
//
#include <hip/hip_runtime.h>
#include <hip/hip_bf16.h>

// Problem sizes (fixed by the reference)
#define B_DIM 8192
#define IN_DIM 2048
#define H_DIM 2048

// GEMM tile config: 256x256 tile, BK=32, 8 waves (2Mx4N), 4 LDS buffers
#define BM 256
#define BN 256
#define BK 32
#define NT 128        // total K-tiles (K = 4096 = NT*BK)
#define NT_HALF 64    // source switch at k = 2048
#define NBUF 4        // 4 x 32KB = 128KB LDS

typedef __attribute__((ext_vector_type(8))) short short8;   // 8 bf16 = 4 VGPRs
typedef __attribute__((ext_vector_type(4))) float f32x4;    // MFMA accum

__device__ __forceinline__ unsigned short f2bf(float f) {
    unsigned u = __builtin_bit_cast(unsigned, f);
    u += 0x7fffu + ((u >> 16) & 1u);
    return (unsigned short)(u >> 16);
}

// ---------------------------------------------------------------------------
// fp32 -> bf16 conversion, vectorized
// ---------------------------------------------------------------------------
__global__ void __launch_bounds__(256) cvt_f32_bf16(const float* __restrict__ in,
                                                    unsigned short* __restrict__ out,
                                                    int n8) {
    int i = blockIdx.x * blockDim.x + threadIdx.x;
    const int stride = gridDim.x * blockDim.x;
    for (; i < n8; i += stride) {
        const float4* p = (const float4*)in + (size_t)i * 2;
        float4 f0 = p[0], f1 = p[1];
        uint4 o;
        o.x = (unsigned)f2bf(f0.x) | ((unsigned)f2bf(f0.y) << 16);
        o.y = (unsigned)f2bf(f0.z) | ((unsigned)f2bf(f0.w) << 16);
        o.z = (unsigned)f2bf(f1.x) | ((unsigned)f2bf(f1.y) << 16);
        o.w = (unsigned)f2bf(f1.z) | ((unsigned)f2bf(f1.w) << 16);
        ((uint4*)out)[i] = o;
    }
}

// ---------------------------------------------------------------------------
// Deep-pipelined 256x256 GEMM core.
//
// LDS buffer b (32KB each): A-tile [256 rows][32 cols] bf16 at b*32768,
// B-tile at +16384.  Rows are 64B; data is stored with a 16B-chunk XOR
// swizzle: chunk' = chunk ^ ((row>>1)&3).  global_load_lds writes linearly
// (LDS dest = base + tid*16), so the swizzle is applied by PERMUTING THE
// GLOBAL SOURCE address (rule: both-sides-or-neither).  ds_read_b128 of a
// fragment applies the same XOR -> 8 distinct 4-bank groups per quarter,
// 2-way max (free).
//
// Pipeline (1 barrier per K-tile, counted vmcnt, never 0 in main loop):
//   iter t: STAGE(t+2 -> buf[(t+2)%4]);  vmcnt(4)  (tile t+1 landed);
//           barrier;  read fb (tile t, 4x b128) + prefetch faNXT (tile t+1,
//           8x b128);  setprio(1); 32 MFMA on faCUR x fb; setprio(0).
// Write-after-read safety: writes to buf[x%4] issue at iter x-2, >= 1 full
// barrier after all waves' reads of tile x-4 are register-complete.
// Tile landing: vmcnt(4) at iter t drains tile t+1's 4 loads (FIFO),
// leaving tile t+2's 4 in flight.
// ---------------------------------------------------------------------------

#define STAGE(T, BUF)                                                          \
  do {                                                                         \
    const int _t = (T);                                                        \
    const unsigned short* _sa = (_t < NT_HALF) ? Asrc0 : Asrc1;                \
    const unsigned short* _sb = (_t < NT_HALF) ? Bsrc0 : Bsrc1;                \
    const int _k = (_t & (NT_HALF - 1)) * BK;                                  \
    char* _la = lds + (BUF) * 32768;                                           \
    __builtin_amdgcn_global_load_lds(                                          \
        (const __attribute__((address_space(1))) void*)                        \
            (_sa + (size_t)(brow + s_r) * 2048 + _k + s_co),                   \
        (__attribute__((address_space(3))) void*)(_la + tid * 16), 16, 0, 0);  \
    __builtin_amdgcn_global_load_lds(                                          \
        (const __attribute__((address_space(1))) void*)                        \
            (_sa + (size_t)(brow + s_r + 128) * 2048 + _k + s_co),             \
        (__attribute__((address_space(3))) void*)(_la + 8192 + tid * 16),      \
        16, 0, 0);                                                             \
    __builtin_amdgcn_global_load_lds(                                          \
        (const __attribute__((address_space(1))) void*)                        \
            (_sb + (size_t)(bcol + s_r) * 2048 + _k + s_co),                   \
        (__attribute__((address_space(3))) void*)(_la + 16384 + tid * 16),     \
        16, 0, 0);                                                             \
    __builtin_amdgcn_global_load_lds(                                          \
        (const __attribute__((address_space(1))) void*)                        \
            (_sb + (size_t)(bcol + s_r + 128) * 2048 + _k + s_co),             \
        (__attribute__((address_space(3))) void*)(_la + 24576 + tid * 16),     \
        16, 0, 0);                                                             \
  } while (0)

#define G_ITER(T, CUR, NXT, DO_STAGE, VMC)                                     \
  {                                                                            \
    if (DO_STAGE) { STAGE((T) + 2, ((T) + 2) & 3); }                           \
    asm volatile("s_waitcnt vmcnt(" VMC ")" ::: "memory");                     \
    __builtin_amdgcn_s_barrier();                                              \
    asm volatile("" ::: "memory");                                             \
    {                                                                          \
      const char* _pb = lds + ((T) & 3) * 32768;                               \
      _Pragma("unroll") for (int _nf = 0; _nf < 4; ++_nf)                      \
          fb[_nf] = *(const short8*)(_pb + offB[_nf]);                         \
    }                                                                          \
    if ((T) + 1 < NT) {                                                        \
      const char* _pa = lds + (((T) + 1) & 3) * 32768;                         \
      _Pragma("unroll") for (int _mf = 0; _mf < 8; ++_mf)                      \
          fa##NXT[_mf] = *(const short8*)(_pa + offA[_mf]);                    \
    }                                                                          \
    __builtin_amdgcn_s_setprio(1);                                             \
    _Pragma("unroll") for (int _mf = 0; _mf < 8; ++_mf)                        \
        _Pragma("unroll") for (int _nf = 0; _nf < 4; ++_nf)                    \
            acc[_mf][_nf] = __builtin_amdgcn_mfma_f32_16x16x32_bf16(           \
                fa##CUR[_mf], fb[_nf], acc[_mf][_nf], 0, 0, 0);                \
    __builtin_amdgcn_s_setprio(0);                                             \
  }

#define GEMM_CORE(A0P, B0P, A1P, B1P)                                          \
    __shared__ __align__(128) char lds[NBUF * 32768];                          \
    f32x4 acc[8][4] = {};                                                      \
    short8 fa0[8], fa1[8], fb[4];                                              \
    const int tid = threadIdx.x;                                               \
    const int wv = tid >> 6;                                                   \
    const int wm = wv >> 2, wn = wv & 3;                                       \
    const int fr = (tid & 63) & 15;                                            \
    const int fq = (tid & 63) >> 4;                                            \
    const int s_r = tid >> 2;                                                  \
    const int s_co = (((tid & 3) ^ ((s_r >> 1) & 3)) << 3);                    \
    const unsigned short* Asrc0 = (A0P);                                       \
    const unsigned short* Asrc1 = (A1P);                                       \
    const unsigned short* Bsrc0 = (B0P);                                       \
    const unsigned short* Bsrc1 = (B1P);                                       \
    int offA[8], offB[4];                                                      \
    _Pragma("unroll") for (int _i = 0; _i < 8; ++_i) {                         \
      const int _r = wm * 128 + _i * 16 + fr;                                  \
      offA[_i] = _r * 64 + ((fq ^ ((_r >> 1) & 3)) << 4);                      \
    }                                                                          \
    _Pragma("unroll") for (int _i = 0; _i < 4; ++_i) {                         \
      const int _r = wn * 64 + _i * 16 + fr;                                   \
      offB[_i] = 16384 + _r * 64 + ((fq ^ ((_r >> 1) & 3)) << 4);              \
    }                                                                          \
    STAGE(0, 0);                                                               \
    STAGE(1, 1);                                                               \
    asm volatile("s_waitcnt vmcnt(4)" ::: "memory");                           \
    __builtin_amdgcn_s_barrier();                                              \
    asm volatile("" ::: "memory");                                             \
    _Pragma("unroll") for (int _i = 0; _i < 8; ++_i)                           \
        fa0[_i] = *(const short8*)(lds + offA[_i]);                            \
    for (int t = 0; t < 124; t += 4) {                                         \
      G_ITER(t, 0, 1, 1, "4");                                                 \
      G_ITER(t + 1, 1, 0, 1, "4");                                             \
      G_ITER(t + 2, 0, 1, 1, "4");                                             \
      G_ITER(t + 3, 1, 0, 1, "4");                                             \
    }                                                                          \
    G_ITER(124, 0, 1, 1, "4");                                                 \
    G_ITER(125, 1, 0, 1, "4");                                                 \
    G_ITER(126, 0, 1, 0, "0");                                                 \
    G_ITER(127, 1, 0, 0, "0");

// ---------------------------------------------------------------------------
// Kernel 1: r and z gates.  grid = 512: [0,256) -> r, [256,512) -> z
// ---------------------------------------------------------------------------
__global__ void __launch_bounds__(512, 2) gemm_rz(
    const unsigned short* __restrict__ xb, const unsigned short* __restrict__ hb,
    const unsigned short* __restrict__ Wir, const unsigned short* __restrict__ Whr,
    const unsigned short* __restrict__ Wiz, const unsigned short* __restrict__ Whz,
    const float* __restrict__ b_ir, const float* __restrict__ b_iz,
    const float* __restrict__ h_f32,
    float* __restrict__ out_r, float* __restrict__ out_z,
    unsigned short* __restrict__ rh)
{
    int bid = blockIdx.x;
    const int is_z = bid >= 256;
    if (is_z) bid -= 256;
    const int brow = (bid & 31) << 8;   // 32 M-tiles
    const int bcol = (bid >> 5) << 8;   // 8 N-tiles

    const unsigned short* Wi = is_z ? Wiz : Wir;
    const unsigned short* Wh = is_z ? Whz : Whr;

    GEMM_CORE(xb, Wi, hb, Wh)

    const float* bias = is_z ? b_iz : b_ir;
    float* outp = is_z ? out_z : out_r;

#pragma unroll
    for (int nf = 0; nf < 4; ++nf) {
        const int col = bcol + wn * 64 + nf * 16 + fr;
        const float bv = bias[col];
#pragma unroll
        for (int mf = 0; mf < 8; ++mf) {
            const int row0 = brow + wm * 128 + mf * 16 + fq * 4;
#pragma unroll
            for (int v = 0; v < 4; ++v) {
                const size_t idx = (size_t)(row0 + v) * 2048 + col;
                float s = acc[mf][nf][v] + bv;
                s = 1.0f / (1.0f + __expf(-s));
                outp[idx] = s;
                if (!is_z) rh[idx] = f2bf(s * h_f32[idx]);
            }
        }
    }
}

// ---------------------------------------------------------------------------
// Kernel 2: n gate + h_t.  grid = 256 blocks.
// ---------------------------------------------------------------------------
__global__ void __launch_bounds__(512, 2) gemm_n(
    const unsigned short* __restrict__ xb, const unsigned short* __restrict__ rh,
    const unsigned short* __restrict__ Win, const unsigned short* __restrict__ Whn,
    const float* __restrict__ b_in,
    const float* __restrict__ h_f32, const float* __restrict__ out_z,
    float* __restrict__ out_n, float* __restrict__ out_ht)
{
    const int bid = blockIdx.x;
    const int brow = (bid & 31) << 8;
    const int bcol = (bid >> 5) << 8;

    GEMM_CORE(xb, Win, rh, Whn)

#pragma unroll
    for (int nf = 0; nf < 4; ++nf) {
        const int col = bcol + wn * 64 + nf * 16 + fr;
        const float bv = b_in[col];
#pragma unroll
        for (int mf = 0; mf < 8; ++mf) {
            const int row0 = brow + wm * 128 + mf * 16 + fq * 4;
#pragma unroll
            for (int v = 0; v < 4; ++v) {
                const size_t idx = (size_t)(row0 + v) * 2048 + col;
                const float tn = tanhf(acc[mf][nf][v] + bv);
                out_n[idx] = tn;
                const float zv = out_z[idx];
                const float hv = h_f32[idx];
                out_ht[idx] = (1.0f - zv) * tn + zv * hv;
            }
        }
    }
}

// ---------------------------------------------------------------------------
// Launch
// ---------------------------------------------------------------------------
extern "C" void kernel_launch(void* const* d_in, const int* in_sizes, int n_in,
                              void* d_out, int out_size, void* d_ws, size_t ws_size,
                              hipStream_t stream) {
    const float* x    = (const float*)d_in[0];
    const float* h    = (const float*)d_in[1];
    const float* W_ir = (const float*)d_in[2];
    const float* b_ir = (const float*)d_in[3];
    const float* W_hr = (const float*)d_in[4];
    const float* W_iz = (const float*)d_in[5];
    const float* b_iz = (const float*)d_in[6];
    const float* W_hz = (const float*)d_in[7];
    const float* W_in = (const float*)d_in[8];
    const float* b_in = (const float*)d_in[9];
    const float* W_hn = (const float*)d_in[10];

    const size_t NBH = (size_t)B_DIM * H_DIM;   // 16,777,216
    const size_t NW  = (size_t)H_DIM * IN_DIM;  // 4,194,304

    float* out_ht = (float*)d_out;
    float* out_r  = out_ht + NBH;
    float* out_z  = out_r + NBH;
    float* out_n  = out_z + NBH;

    unsigned short* ws   = (unsigned short*)d_ws;
    unsigned short* xb   = ws;
    unsigned short* hb   = xb + NBH;
    unsigned short* wirb = hb + NBH;
    unsigned short* whrb = wirb + NW;
    unsigned short* wizb = whrb + NW;
    unsigned short* whzb = wizb + NW;
    unsigned short* winb = whzb + NW;
    unsigned short* whnb = winb + NW;
    unsigned short* rh   = whnb + NW;

    const int CVT_BLOCKS = 2048;
    cvt_f32_bf16<<<CVT_BLOCKS, 256, 0, stream>>>(x, xb, (int)(NBH / 8));
    cvt_f32_bf16<<<CVT_BLOCKS, 256, 0, stream>>>(h, hb, (int)(NBH / 8));
    cvt_f32_bf16<<<CVT_BLOCKS, 256, 0, stream>>>(W_ir, wirb, (int)(NW / 8));
    cvt_f32_bf16<<<CVT_BLOCKS, 256, 0, stream>>>(W_hr, whrb, (int)(NW / 8));
    cvt_f32_bf16<<<CVT_BLOCKS, 256, 0, stream>>>(W_iz, wizb, (int)(NW / 8));
    cvt_f32_bf16<<<CVT_BLOCKS, 256, 0, stream>>>(W_hz, whzb, (int)(NW / 8));
    cvt_f32_bf16<<<CVT_BLOCKS, 256, 0, stream>>>(W_in, winb, (int)(NW / 8));
    cvt_f32_bf16<<<CVT_BLOCKS, 256, 0, stream>>>(W_hn, whnb, (int)(NW / 8));

    gemm_rz<<<512, 512, 0, stream>>>(xb, hb, wirb, whrb, wizb, whzb,
                                     b_ir, b_iz, h, out_r, out_z, rh);

    gemm_n<<<256, 512, 0, stream>>>(xb, rh, winb, whnb, b_in, h, out_z,
                                    out_n, out_ht);
}

// Round 6
// 940.748 us; speedup vs baseline: 1.2991x; 1.0886x over previous
//
#include <hip/hip_runtime.h>
#include <hip/hip_bf16.h>

// Problem sizes (fixed by the reference)
#define B_DIM 8192
#define IN_DIM 2048
#define H_DIM 2048

// 8-phase 256x256 template: BK=64, 8 waves (2M x 4N), 2 LDS buffers (2x64KB)
// K = 4096 -> 64 K-tiles; source switch (x->h / Wi->Wh) at tile 32.
#define NTILE 32

typedef __attribute__((ext_vector_type(8))) short short8;   // 8 bf16 = 4 VGPRs
typedef __attribute__((ext_vector_type(4))) float f32x4;    // MFMA accum

__device__ __forceinline__ unsigned short f2bf(float f) {
    unsigned u = __builtin_bit_cast(unsigned, f);
    u += 0x7fffu + ((u >> 16) & 1u);
    return (unsigned short)(u >> 16);
}

// ---------------------------------------------------------------------------
// fp32 -> bf16 conversion, vectorized
// ---------------------------------------------------------------------------
__global__ void __launch_bounds__(256) cvt_f32_bf16(const float* __restrict__ in,
                                                    unsigned short* __restrict__ out,
                                                    int n8) {
    int i = blockIdx.x * blockDim.x + threadIdx.x;
    const int stride = gridDim.x * blockDim.x;
    for (; i < n8; i += stride) {
        const float4* p = (const float4*)in + (size_t)i * 2;
        float4 f0 = p[0], f1 = p[1];
        uint4 o;
        o.x = (unsigned)f2bf(f0.x) | ((unsigned)f2bf(f0.y) << 16);
        o.y = (unsigned)f2bf(f0.z) | ((unsigned)f2bf(f0.w) << 16);
        o.z = (unsigned)f2bf(f1.x) | ((unsigned)f2bf(f1.y) << 16);
        o.w = (unsigned)f2bf(f1.z) | ((unsigned)f2bf(f1.w) << 16);
        ((uint4*)out)[i] = o;
    }
}

// ---------------------------------------------------------------------------
// 8-phase 256x256 GEMM core (4 phases per K-tile of BK=64, 2 K-tiles = 8).
//
// LDS: buf b at b*65536.  A-tile [256 rows][64 cols] bf16 at +0 (32KB),
// B-tile at +32768.  Rows are 128B = 8 chunks of 16B; chunk is stored
// XOR-swizzled: chunk' = chunk ^ (row & 7).  global_load_lds writes
// linearly, so the swizzle is applied by pre-swizzling the GLOBAL source
// column (both-sides-or-neither).  Frag reads apply the same XOR; since
// all frag-row bases are multiples of 8, the XOR key is fr&7 -> every
// 16-lane group spreads over all 8 chunk slots = 2-way max (free).
//
// Per K-tile t (computing from buf[t&1]), phases:
//   P1: stage(t+1,h1); read a0(8)+b0(4); BAR; 16 MFMA q(0,0); BAR
//   P2: stage(t+1,h2); read b1(4);       BAR; 16 MFMA q(0,2); BAR
//   P3: stage(t+1,h3); read a1(8);       BAR; 16 MFMA q(4,0); BAR
//   P4: stage(t+2,h0); vmcnt(2);         BAR; 16 MFMA q(4,2); BAR
// Half-tiles: h0=A rows 0-127, h1=A rows 128-255, h2=B rows 0-127,
// h3=B rows 128-255; each = 2 global_load_lds (512 thr x 16B x 2).
//
// vmcnt ledger (2 loads/phase, FIFO): at P(t,4) outstanding =
// tile t+1's 8 (issued P(t-1,4),P(t,1..3)) + t+2 h0's 2 (just issued)
// -> vmcnt(2) drains tile t+1, keeps t+2's h0 in flight.  Never 0 in
// the main loop (T4).  WAR: buf[t&1] last read at P3 (a1); overwriting
// stage (t+2,h0 -> buf[t&1]) issues at P4, after P3's closing barrier;
// h1..h3 of any tile target the buffer whose reads finished >=2 barriers
// earlier.  Register lifetimes: a0 read P1 last used P2; b0 read P1 last
// used P3; b1 read P2 used P2,P4; a1 read P3 used P3,P4 -> no overlap
// with next tile's P1 reads (they follow P4's vmcnt+barrier).
// ---------------------------------------------------------------------------

#define BARRIER do { __builtin_amdgcn_s_barrier(); \
                     asm volatile("" ::: "memory"); } while (0)

#define STG_HALF(TT, H)                                                        \
  do {                                                                         \
    const int _t = (TT);                                                       \
    const int _k = (_t & (NTILE - 1)) * 64;                                    \
    const unsigned short* _src;                                                \
    int _rbase;                                                                \
    if ((H) < 2) { _src = (_t < NTILE) ? Asrc0 : Asrc1; _rbase = brow + (H) * 128; } \
    else         { _src = (_t < NTILE) ? Bsrc0 : Bsrc1; _rbase = bcol + ((H) - 2) * 128; } \
    char* _dst = lds + ((_t) & 1) * 65536 + (H) * 16384;                       \
    __builtin_amdgcn_global_load_lds(                                          \
        (const __attribute__((address_space(1))) void*)                        \
            (_src + (size_t)(_rbase + s_r) * 2048 + _k + s_c),                 \
        (__attribute__((address_space(3))) void*)(_dst + tid * 16), 16, 0, 0); \
    __builtin_amdgcn_global_load_lds(                                          \
        (const __attribute__((address_space(1))) void*)                        \
            (_src + (size_t)(_rbase + 64 + s_r) * 2048 + _k + s_c),            \
        (__attribute__((address_space(3))) void*)(_dst + 8192 + tid * 16),     \
        16, 0, 0);                                                             \
  } while (0)

#define RD_A(DST, MH)                                                          \
    _Pragma("unroll") for (int _mf = 0; _mf < 4; ++_mf)                        \
      _Pragma("unroll") for (int _ks = 0; _ks < 2; ++_ks)                      \
        DST[_mf * 2 + _ks] =                                                   \
            *(const short8*)(bp + Abase + (MH) * 8192 + _mf * 2048 + cA[_ks]);

#define RD_B(DST, NH)                                                          \
    _Pragma("unroll") for (int _nf = 0; _nf < 2; ++_nf)                        \
      _Pragma("unroll") for (int _ks = 0; _ks < 2; ++_ks)                      \
        DST[_nf * 2 + _ks] =                                                   \
            *(const short8*)(bp + Bbase + (NH) * 4096 + _nf * 2048 + cA[_ks]);

#define QUAD(AM0, AN0, AFR, BFR)                                               \
    _Pragma("unroll") for (int _mf = 0; _mf < 4; ++_mf)                        \
      _Pragma("unroll") for (int _nf = 0; _nf < 2; ++_nf)                      \
        _Pragma("unroll") for (int _ks = 0; _ks < 2; ++_ks)                    \
          acc[(AM0) + _mf][(AN0) + _nf] =                                      \
              __builtin_amdgcn_mfma_f32_16x16x32_bf16(                         \
                  AFR[_mf * 2 + _ks], BFR[_nf * 2 + _ks],                      \
                  acc[(AM0) + _mf][(AN0) + _nf], 0, 0, 0);

#define TILE_BODY(T, S1, S2, S3, S4, WAITSTR)                                  \
  {                                                                            \
    const char* bp = lds + ((T) & 1) * 65536;                                  \
    S1;                                                                        \
    RD_A(a0, 0) RD_B(b0, 0)                                                    \
    BARRIER;                                                                   \
    __builtin_amdgcn_s_setprio(1);                                             \
    QUAD(0, 0, a0, b0)                                                         \
    __builtin_amdgcn_s_setprio(0);                                             \
    BARRIER;                                                                   \
    S2;                                                                        \
    RD_B(b1, 1)                                                                \
    BARRIER;                                                                   \
    __builtin_amdgcn_s_setprio(1);                                             \
    QUAD(0, 2, a0, b1)                                                         \
    __builtin_amdgcn_s_setprio(0);                                             \
    BARRIER;                                                                   \
    S3;                                                                        \
    RD_A(a1, 1)                                                                \
    BARRIER;                                                                   \
    __builtin_amdgcn_s_setprio(1);                                             \
    QUAD(4, 0, a1, b0)                                                         \
    __builtin_amdgcn_s_setprio(0);                                             \
    BARRIER;                                                                   \
    S4;                                                                        \
    asm volatile("s_waitcnt vmcnt(" WAITSTR ")" ::: "memory");                 \
    BARRIER;                                                                   \
    __builtin_amdgcn_s_setprio(1);                                             \
    QUAD(4, 2, a1, b1)                                                         \
    __builtin_amdgcn_s_setprio(0);                                             \
    BARRIER;                                                                   \
  }

#define GEMM_CORE(A0P, B0P, A1P, B1P)                                          \
    __shared__ __align__(128) char lds[131072];                                \
    f32x4 acc[8][4] = {};                                                      \
    short8 a0[8], a1[8], b0[4], b1[4];                                         \
    const int tid = threadIdx.x;                                               \
    const int wv = tid >> 6;                                                   \
    const int wm = wv >> 2, wn = wv & 3;                                       \
    const int fr = (tid & 63) & 15;                                            \
    const int fq = (tid & 63) >> 4;                                            \
    const int s_r = tid >> 3;                              /* 0..63 */         \
    const int s_c = (((tid & 7) ^ (s_r & 7)) << 3);        /* elems  */        \
    const unsigned short* Asrc0 = (A0P);                                       \
    const unsigned short* Asrc1 = (A1P);                                       \
    const unsigned short* Bsrc0 = (B0P);                                       \
    const unsigned short* Bsrc1 = (B1P);                                       \
    const int Abase = (wm * 128 + fr) * 128;                                   \
    const int Bbase = 32768 + (wn * 64 + fr) * 128;                            \
    int cA[2];                                                                 \
    cA[0] = ((fq ^ (fr & 7)) << 4);                                            \
    cA[1] = (((4 + fq) ^ (fr & 7)) << 4);                                      \
    STG_HALF(0, 0); STG_HALF(0, 1); STG_HALF(0, 2); STG_HALF(0, 3);            \
    STG_HALF(1, 0);                                                            \
    asm volatile("s_waitcnt vmcnt(2)" ::: "memory");                           \
    BARRIER;                                                                   \
    for (int t = 0; t < 62; ++t) {                                             \
      TILE_BODY(t, STG_HALF(t + 1, 1), STG_HALF(t + 1, 2),                     \
                STG_HALF(t + 1, 3), STG_HALF(t + 2, 0), "2")                   \
    }                                                                          \
    TILE_BODY(62, STG_HALF(63, 1), STG_HALF(63, 2), STG_HALF(63, 3),           \
              (void)0, "0")                                                    \
    TILE_BODY(63, (void)0, (void)0, (void)0, (void)0, "0")

// ---------------------------------------------------------------------------
// Kernel 1: r and z gates.  grid = 512: [0,256) -> r, [256,512) -> z
// ---------------------------------------------------------------------------
__global__ void __launch_bounds__(512, 2) gemm_rz(
    const unsigned short* __restrict__ xb, const unsigned short* __restrict__ hb,
    const unsigned short* __restrict__ Wir, const unsigned short* __restrict__ Whr,
    const unsigned short* __restrict__ Wiz, const unsigned short* __restrict__ Whz,
    const float* __restrict__ b_ir, const float* __restrict__ b_iz,
    const float* __restrict__ h_f32,
    float* __restrict__ out_r, float* __restrict__ out_z,
    unsigned short* __restrict__ rh)
{
    int bid = blockIdx.x;
    const int is_z = bid >= 256;
    if (is_z) bid -= 256;
    const int brow = (bid & 31) << 8;   // 32 M-tiles
    const int bcol = (bid >> 5) << 8;   // 8 N-tiles

    const unsigned short* Wi = is_z ? Wiz : Wir;
    const unsigned short* Wh = is_z ? Whz : Whr;

    GEMM_CORE(xb, Wi, hb, Wh)

    const float* bias = is_z ? b_iz : b_ir;
    float* outp = is_z ? out_z : out_r;

#pragma unroll
    for (int an = 0; an < 4; ++an) {
        const int col = bcol + wn * 64 + an * 16 + fr;
        const float bv = bias[col];
#pragma unroll
        for (int am = 0; am < 8; ++am) {
            const int row0 = brow + wm * 128 + am * 16 + fq * 4;
#pragma unroll
            for (int v = 0; v < 4; ++v) {
                const size_t idx = (size_t)(row0 + v) * 2048 + col;
                float s = acc[am][an][v] + bv;
                s = 1.0f / (1.0f + __expf(-s));
                outp[idx] = s;
                if (!is_z) rh[idx] = f2bf(s * h_f32[idx]);
            }
        }
    }
}

// ---------------------------------------------------------------------------
// Kernel 2: n gate + h_t.  grid = 256 blocks.
// ---------------------------------------------------------------------------
__global__ void __launch_bounds__(512, 2) gemm_n(
    const unsigned short* __restrict__ xb, const unsigned short* __restrict__ rh,
    const unsigned short* __restrict__ Win, const unsigned short* __restrict__ Whn,
    const float* __restrict__ b_in,
    const float* __restrict__ h_f32, const float* __restrict__ out_z,
    float* __restrict__ out_n, float* __restrict__ out_ht)
{
    const int bid = blockIdx.x;
    const int brow = (bid & 31) << 8;
    const int bcol = (bid >> 5) << 8;

    GEMM_CORE(xb, Win, rh, Whn)

#pragma unroll
    for (int an = 0; an < 4; ++an) {
        const int col = bcol + wn * 64 + an * 16 + fr;
        const float bv = b_in[col];
#pragma unroll
        for (int am = 0; am < 8; ++am) {
            const int row0 = brow + wm * 128 + am * 16 + fq * 4;
#pragma unroll
            for (int v = 0; v < 4; ++v) {
                const size_t idx = (size_t)(row0 + v) * 2048 + col;
                const float tn = tanhf(acc[am][an][v] + bv);
                out_n[idx] = tn;
                const float zv = out_z[idx];
                const float hv = h_f32[idx];
                out_ht[idx] = (1.0f - zv) * tn + zv * hv;
            }
        }
    }
}

// ---------------------------------------------------------------------------
// Launch
// ---------------------------------------------------------------------------
extern "C" void kernel_launch(void* const* d_in, const int* in_sizes, int n_in,
                              void* d_out, int out_size, void* d_ws, size_t ws_size,
                              hipStream_t stream) {
    const float* x    = (const float*)d_in[0];
    const float* h    = (const float*)d_in[1];
    const float* W_ir = (const float*)d_in[2];
    const float* b_ir = (const float*)d_in[3];
    const float* W_hr = (const float*)d_in[4];
    const float* W_iz = (const float*)d_in[5];
    const float* b_iz = (const float*)d_in[6];
    const float* W_hz = (const float*)d_in[7];
    const float* W_in = (const float*)d_in[8];
    const float* b_in = (const float*)d_in[9];
    const float* W_hn = (const float*)d_in[10];

    const size_t NBH = (size_t)B_DIM * H_DIM;   // 16,777,216
    const size_t NW  = (size_t)H_DIM * IN_DIM;  // 4,194,304

    float* out_ht = (float*)d_out;
    float* out_r  = out_ht + NBH;
    float* out_z  = out_r + NBH;
    float* out_n  = out_z + NBH;

    unsigned short* ws   = (unsigned short*)d_ws;
    unsigned short* xb   = ws;
    unsigned short* hb   = xb + NBH;
    unsigned short* wirb = hb + NBH;
    unsigned short* whrb = wirb + NW;
    unsigned short* wizb = whrb + NW;
    unsigned short* whzb = wizb + NW;
    unsigned short* winb = whzb + NW;
    unsigned short* whnb = winb + NW;
    unsigned short* rh   = whnb + NW;

    const int CVT_BLOCKS = 2048;
    cvt_f32_bf16<<<CVT_BLOCKS, 256, 0, stream>>>(x, xb, (int)(NBH / 8));
    cvt_f32_bf16<<<CVT_BLOCKS, 256, 0, stream>>>(h, hb, (int)(NBH / 8));
    cvt_f32_bf16<<<CVT_BLOCKS, 256, 0, stream>>>(W_ir, wirb, (int)(NW / 8));
    cvt_f32_bf16<<<CVT_BLOCKS, 256, 0, stream>>>(W_hr, whrb, (int)(NW / 8));
    cvt_f32_bf16<<<CVT_BLOCKS, 256, 0, stream>>>(W_iz, wizb, (int)(NW / 8));
    cvt_f32_bf16<<<CVT_BLOCKS, 256, 0, stream>>>(W_hz, whzb, (int)(NW / 8));
    cvt_f32_bf16<<<CVT_BLOCKS, 256, 0, stream>>>(W_in, winb, (int)(NW / 8));
    cvt_f32_bf16<<<CVT_BLOCKS, 256, 0, stream>>>(W_hn, whnb, (int)(NW / 8));

    gemm_rz<<<512, 512, 0, stream>>>(xb, hb, wirb, whrb, wizb, whzb,
                                     b_ir, b_iz, h, out_r, out_z, rh);

    gemm_n<<<256, 512, 0, stream>>>(xb, rh, winb, whnb, b_in, h, out_z,
                                    out_n, out_ht);
}